// Round 8
// baseline (24.269 us; speedup 1.0000x reference)
//
#include <hip/hip_runtime.h>
#include <hip/hip_fp16.h>

// bg: (1,4,32,32,32,16) f32 ; gm: (1,1,128,128,128) f32 ; out: (1,4,128,128,128) f32
//
// v8: pipelined k-deep tile. 8(i) x 8(j) x 64(k) per 512-thread block
// (512 blocks, 2/CU). Thread = (li,lj,kq): 8 voxels in 2 chunks of 32 k.
// LDS: [xy 16][z-window 17][t 16][ch 4] fp16, node stride 36 dw (144B).
// Pre-stage z 0..9 -> barrier -> {issue loads z 10..16 | interp chunk 0 |
// pack+ds_write} -> barrier -> interp chunk 1. Stage writes (z>=10) are
// disjoint from chunk-0 reads (z<=9), so one barrier per iter suffices.

#define S_ (31.0f / 127.0f)
#define CH_STRIDE 524288
#define TOTAL 2097152

#define NZW 17
#define NODE_DW 36
#define XSTRIDE (4 * NZW * NODE_DW)   // 2448
#define YSTRIDE (NZW * NODE_DW)       // 612
#define LDS_DW (16 * NZW * NODE_DW)   // 9792 dw = 39168 B

#define PK(x, y) __builtin_bit_cast(float, __floats2half2_rn((x), (y)))
#define H2(f) __builtin_bit_cast(__half2, f)

#define CHUNK(KK, G4, IDX)                                                     \
    {                                                                          \
        float o0[4], o1[4], o2[4], o3[4];                                      \
        _Pragma("unroll")                                                      \
        for (int v = 0; v < 4; ++v) {                                          \
            const float g = (v == 0) ? (G4).x : (v == 1) ? (G4).y              \
                          : (v == 2) ? (G4).z : (G4).w;                        \
            float t = fminf(fmaxf(g * 15.0f, 0.0f), 15.0f);                    \
            const int t0 = min((int)t, 14);                                    \
            const float ft = t - (float)t0;                                    \
            const __half2 ft2 = __float2half2_rn(ft);                          \
            const float zf = fminf((float)((KK) + v) * S_, 31.0f);             \
            const int z0g = (int)zf;                                           \
            const float fz = zf - (float)z0g;                                  \
            const int ziA = z0g - z_base;                                      \
            const int ziB = min(min(z0g + 1, 31) - z_base, NZW - 1);           \
            const __half2 fz2 = __float2half2_rn(fz);                          \
            const int CZ0 = ziA * NODE_DW + (t0 << 1);                         \
            const int CZ1 = ziB * NODE_DW + (t0 << 1);                         \
            const float2 a00lo = *(const float2*)&lds[AX0 + BY0 + CZ0];        \
            const float2 a00hi = *(const float2*)&lds[AX0 + BY0 + CZ0 + 2];    \
            const float2 a01lo = *(const float2*)&lds[AX0 + BY1 + CZ0];        \
            const float2 a01hi = *(const float2*)&lds[AX0 + BY1 + CZ0 + 2];    \
            const float2 a10lo = *(const float2*)&lds[AX1 + BY0 + CZ0];        \
            const float2 a10hi = *(const float2*)&lds[AX1 + BY0 + CZ0 + 2];    \
            const float2 a11lo = *(const float2*)&lds[AX1 + BY1 + CZ0];        \
            const float2 a11hi = *(const float2*)&lds[AX1 + BY1 + CZ0 + 2];    \
            const float2 b00lo = *(const float2*)&lds[AX0 + BY0 + CZ1];        \
            const float2 b00hi = *(const float2*)&lds[AX0 + BY0 + CZ1 + 2];    \
            const float2 b01lo = *(const float2*)&lds[AX0 + BY1 + CZ1];        \
            const float2 b01hi = *(const float2*)&lds[AX0 + BY1 + CZ1 + 2];    \
            const float2 b10lo = *(const float2*)&lds[AX1 + BY0 + CZ1];        \
            const float2 b10hi = *(const float2*)&lds[AX1 + BY0 + CZ1 + 2];    \
            const float2 b11lo = *(const float2*)&lds[AX1 + BY1 + CZ1];        \
            const float2 b11hi = *(const float2*)&lds[AX1 + BY1 + CZ1 + 2];    \
            __half2 Plo01 = __hmul2(W00, H2(a00lo.x));                         \
            __half2 Plo23 = __hmul2(W00, H2(a00lo.y));                         \
            __half2 Phi01 = __hmul2(W00, H2(a00hi.x));                         \
            __half2 Phi23 = __hmul2(W00, H2(a00hi.y));                         \
            Plo01 = __hfma2(W01, H2(a01lo.x), Plo01);                          \
            Plo23 = __hfma2(W01, H2(a01lo.y), Plo23);                          \
            Phi01 = __hfma2(W01, H2(a01hi.x), Phi01);                          \
            Phi23 = __hfma2(W01, H2(a01hi.y), Phi23);                          \
            Plo01 = __hfma2(W10, H2(a10lo.x), Plo01);                          \
            Plo23 = __hfma2(W10, H2(a10lo.y), Plo23);                          \
            Phi01 = __hfma2(W10, H2(a10hi.x), Phi01);                          \
            Phi23 = __hfma2(W10, H2(a10hi.y), Phi23);                          \
            Plo01 = __hfma2(W11, H2(a11lo.x), Plo01);                          \
            Plo23 = __hfma2(W11, H2(a11lo.y), Plo23);                          \
            Phi01 = __hfma2(W11, H2(a11hi.x), Phi01);                          \
            Phi23 = __hfma2(W11, H2(a11hi.y), Phi23);                          \
            __half2 Qlo01 = __hmul2(W00, H2(b00lo.x));                         \
            __half2 Qlo23 = __hmul2(W00, H2(b00lo.y));                         \
            __half2 Qhi01 = __hmul2(W00, H2(b00hi.x));                         \
            __half2 Qhi23 = __hmul2(W00, H2(b00hi.y));                         \
            Qlo01 = __hfma2(W01, H2(b01lo.x), Qlo01);                          \
            Qlo23 = __hfma2(W01, H2(b01lo.y), Qlo23);                          \
            Qhi01 = __hfma2(W01, H2(b01hi.x), Qhi01);                          \
            Qhi23 = __hfma2(W01, H2(b01hi.y), Qhi23);                          \
            Qlo01 = __hfma2(W10, H2(b10lo.x), Qlo01);                          \
            Qlo23 = __hfma2(W10, H2(b10lo.y), Qlo23);                          \
            Qhi01 = __hfma2(W10, H2(b10hi.x), Qhi01);                          \
            Qhi23 = __hfma2(W10, H2(b10hi.y), Qhi23);                          \
            Qlo01 = __hfma2(W11, H2(b11lo.x), Qlo01);                          \
            Qlo23 = __hfma2(W11, H2(b11lo.y), Qlo23);                          \
            Qhi01 = __hfma2(W11, H2(b11hi.x), Qhi01);                          \
            Qhi23 = __hfma2(W11, H2(b11hi.y), Qhi23);                          \
            const __half2 Rlo01 = __hfma2(fz2, __hsub2(Qlo01, Plo01), Plo01);  \
            const __half2 Rlo23 = __hfma2(fz2, __hsub2(Qlo23, Plo23), Plo23);  \
            const __half2 Rhi01 = __hfma2(fz2, __hsub2(Qhi01, Phi01), Phi01);  \
            const __half2 Rhi23 = __hfma2(fz2, __hsub2(Qhi23, Phi23), Phi23);  \
            const __half2 r01 = __hfma2(ft2, __hsub2(Rhi01, Rlo01), Rlo01);    \
            const __half2 r23 = __hfma2(ft2, __hsub2(Rhi23, Rlo23), Rlo23);    \
            o0[v] = __low2float(r01);                                          \
            o1[v] = __high2float(r01);                                         \
            o2[v] = __low2float(r23);                                          \
            o3[v] = __high2float(r23);                                         \
        }                                                                      \
        float4 st;                                                             \
        st.x = o0[0]; st.y = o0[1]; st.z = o0[2]; st.w = o0[3];                \
        *(float4*)&out[(IDX)] = st;                                            \
        st.x = o1[0]; st.y = o1[1]; st.z = o1[2]; st.w = o1[3];                \
        *(float4*)&out[(IDX) + TOTAL] = st;                                    \
        st.x = o2[0]; st.y = o2[1]; st.z = o2[2]; st.w = o2[3];                \
        *(float4*)&out[(IDX) + 2 * TOTAL] = st;                                \
        st.x = o3[0]; st.y = o3[1]; st.z = o3[2]; st.w = o3[3];                \
        *(float4*)&out[(IDX) + 3 * TOTAL] = st;                                \
    }

__global__ __launch_bounds__(512, 4) void bgrid_slice_v8(
    const float* __restrict__ bg,
    const float* __restrict__ gm,
    float* __restrict__ out)
{
    __shared__ __align__(16) float lds[LDS_DW];

    const int tid = threadIdx.x;
    const int b = blockIdx.x;
    const int bk = b & 1;
    const int bj = (b >> 1) & 15;
    const int bi = b >> 5;

    const int i0 = bi * 8, j0 = bj * 8, K0 = bk * 64;
    const int x_base = (int)((float)i0 * S_);
    const int y_base = (int)((float)j0 * S_);
    const int z_base = (int)((float)K0 * S_);

    // ---- pre-stage: zi 0..9 (10 z) * 16 xy * 4 seg = 640 items of 16B ----
    #pragma unroll
    for (int it = 0; it < 2; ++it) {
        const int q = tid + it * 512;
        if (q < 640) {
            const int seg = q & 3;
            const int r = q >> 2;            // xy*10 + zi
            const int zi = r % 10;
            const int xy = r / 10;
            const int gx = min(x_base + (xy >> 2), 31);
            const int gy = min(y_base + (xy & 3), 31);
            const int gz = min(z_base + zi, 31);
            const int gbase = (((gx * 32 + gy) * 32 + gz) << 4) + (seg << 2);
            const float4 L0 = *(const float4*)&bg[gbase];
            const float4 L1 = *(const float4*)&bg[gbase + CH_STRIDE];
            const float4 L2 = *(const float4*)&bg[gbase + 2 * CH_STRIDE];
            const float4 L3 = *(const float4*)&bg[gbase + 3 * CH_STRIDE];
            float4 W0, W1;
            W0.x = PK(L0.x, L1.x); W0.y = PK(L2.x, L3.x);
            W0.z = PK(L0.y, L1.y); W0.w = PK(L2.y, L3.y);
            W1.x = PK(L0.z, L1.z); W1.y = PK(L2.z, L3.z);
            W1.z = PK(L0.w, L1.w); W1.w = PK(L2.w, L3.w);
            const int d = (xy * NZW + zi) * NODE_DW + (seg << 3);
            *(float4*)&lds[d] = W0;
            *(float4*)&lds[d + 4] = W1;
        }
    }

    // ---- per-thread interp constants ----
    const int kq = tid & 7;
    const int lj = (tid >> 3) & 7;
    const int li = tid >> 6;
    const int i = i0 + li, j = j0 + lj;

    const float xf = fminf((float)i * S_, 31.0f);
    const float yf = fminf((float)j * S_, 31.0f);
    const int x0g = (int)xf; const float fx = xf - (float)x0g;
    const int y0g = (int)yf; const float fy = yf - (float)y0g;
    const int AX0 = (x0g - x_base) * XSTRIDE;
    const int AX1 = (min(x0g + 1, 31) - x_base) * XSTRIDE;
    const int BY0 = (y0g - y_base) * YSTRIDE;
    const int BY1 = (min(y0g + 1, 31) - y_base) * YSTRIDE;

    const float wx1 = fx, wx0 = 1.0f - fx;
    const float wy1 = fy, wy0 = 1.0f - fy;
    const __half2 W00 = __float2half2_rn(wx0 * wy0);
    const __half2 W01 = __float2half2_rn(wx0 * wy1);
    const __half2 W10 = __float2half2_rn(wx1 * wy0);
    const __half2 W11 = __float2half2_rn(wx1 * wy1);

    const int kk0 = K0 + (kq << 2);
    const int idx0 = (i << 14) | (j << 7) | kk0;
    const float4 ga = *(const float4*)&gm[idx0];
    const float4 gb = *(const float4*)&gm[idx0 + 32];

    __syncthreads();

    // ---- iter 0: issue stage loads for zi 10..16 (7 z * 16 xy * 4 = 448) ----
    float4 SL0, SL1, SL2, SL3;
    int sd = 0;
    const bool sactive = (tid < 448);      // waves 0-6 full, wave 7 idle
    if (sactive) {
        const int seg = tid & 3;
        const int r = tid >> 2;            // xy*7 + (zi-10)
        const int zi = 10 + r % 7;
        const int xy = r / 7;
        const int gx = min(x_base + (xy >> 2), 31);
        const int gy = min(y_base + (xy & 3), 31);
        const int gz = min(z_base + zi, 31);
        const int gbase = (((gx * 32 + gy) * 32 + gz) << 4) + (seg << 2);
        SL0 = *(const float4*)&bg[gbase];
        SL1 = *(const float4*)&bg[gbase + CH_STRIDE];
        SL2 = *(const float4*)&bg[gbase + 2 * CH_STRIDE];
        SL3 = *(const float4*)&bg[gbase + 3 * CH_STRIDE];
        sd = (xy * NZW + zi) * NODE_DW + (seg << 3);
    }

    // chunk 0: k in [K0, K0+31], reads zi <= 9 (disjoint from stage writes)
    CHUNK(kk0, ga, idx0);

    if (sactive) {
        float4 W0, W1;
        W0.x = PK(SL0.x, SL1.x); W0.y = PK(SL2.x, SL3.x);
        W0.z = PK(SL0.y, SL1.y); W0.w = PK(SL2.y, SL3.y);
        W1.x = PK(SL0.z, SL1.z); W1.y = PK(SL2.z, SL3.z);
        W1.z = PK(SL0.w, SL1.w); W1.w = PK(SL2.w, SL3.w);
        *(float4*)&lds[sd] = W0;
        *(float4*)&lds[sd + 4] = W1;
    }
    __syncthreads();

    // chunk 1: k in [K0+32, K0+63], reads zi <= 16
    CHUNK(kk0 + 32, gb, idx0 + 32);
}

extern "C" void kernel_launch(void* const* d_in, const int* in_sizes, int n_in,
                              void* d_out, int out_size, void* d_ws, size_t ws_size,
                              hipStream_t stream) {
    const float* bg = (const float*)d_in[0];
    const float* gm = (const float*)d_in[1];
    float* out = (float*)d_out;

    dim3 grid(512);    // 16(bi) * 16(bj) * 2(bk)
    dim3 block(512);
    bgrid_slice_v8<<<grid, block, 0, stream>>>(bg, gm, out);
}

// Round 9
// 21.756 us; speedup vs baseline: 1.1155x; 1.1155x over previous
//
#include <hip/hip_runtime.h>
#include <hip/hip_fp16.h>

// bg: (1,4,32,32,32,16) f32 ; gm: (1,1,128,128,128) f32 ; out: (1,4,128,128,128) f32
//
// v9: BARRIER-FREE per-wave staging. Each wave owns a 4(i) x 4(j) x 16(k)
// voxel tile and a private LDS segment of 54 nodes (3x * 3y * 6z), fp16
// [node][16 t][4 ch], node stride 36 dw (144B). The wave stages its own
// nodes (coalesced 16B loads -> cvt_pkrtz -> ds_write_b128) and interps with
// NO __syncthreads: intra-wave ds ordering via lgkmcnt. Wave-level TLP
// overlaps staging (vmcnt stalls) with other waves' LDS/VALU interp.
// Interp body identical to the proven v7 kernel (strides changed only).

#define S_ (31.0f / 127.0f)
#define CH_STRIDE 524288
#define TOTAL 2097152

#define NODE_DW 36                 // 32 data dwords + 4 pad
#define WAVE_DW (54 * NODE_DW)     // 1944 dw = 7776 B per wave
#define XS (18 * NODE_DW)          // x stride (3y * 6z nodes)
#define YS (6 * NODE_DW)           // y stride (6z nodes)

__global__ __launch_bounds__(256, 4) void bgrid_slice_v9(
    const float* __restrict__ bg,
    const float* __restrict__ gm,
    float* __restrict__ out)
{
    __shared__ __align__(16) float lds_all[4 * WAVE_DW];   // 31104 B

    const int tid = threadIdx.x;
    const int wave = tid >> 6;
    const int lane = tid & 63;

    // XCD-chunked swizzle over 2048 blocks (2048 % 8 == 0, bijective).
    const int b = blockIdx.x;
    const int bs = ((b & 7) << 8) + (b >> 3);
    const int gw = (bs << 2) + wave;          // global wave id, 0..8191
    const int wk = gw & 7;                    // k tile (16 k)
    const int wj = (gw >> 3) & 31;            // j tile (4 j)
    const int wi = gw >> 8;                   // i tile (4 i)

    const int i0 = wi * 4, j0 = wj * 4, k0 = wk * 16;
    const int x_base = (int)((float)i0 * S_);
    const int y_base = (int)((float)j0 * S_);
    const int z_base = (int)((float)k0 * S_);

    float* lds = lds_all + wave * WAVE_DW;

    // ---- per-thread voxel coords; issue gm load early ----
    const int kq = lane & 3;
    const int lj = (lane >> 2) & 3;
    const int li = lane >> 4;
    const int i = i0 + li, j = j0 + lj;
    const int kk = k0 + (kq << 2);
    const int idx = (i << 14) | (j << 7) | kk;
    const float4 g4 = *(const float4*)&gm[idx];

    // ---- stage: 54 nodes * 4 segs = 216 items of 16B (fp16 packed) ----
#define PK(x, y) __builtin_bit_cast(float, __floats2half2_rn((x), (y)))
    #pragma unroll
    for (int r = 0; r < 4; ++r) {
        const int q = lane + (r << 6);
        if (q < 216) {
            const int seg = q & 3;
            const int node = q >> 2;          // 0..53
            const int a = node / 18;
            const int rem = node - a * 18;
            const int bb = rem / 6;
            const int cz = rem - bb * 6;
            const int gx = min(x_base + a, 31);
            const int gy = min(y_base + bb, 31);
            const int gz = min(z_base + cz, 31);
            const int gbase = (((gx * 32 + gy) * 32 + gz) << 4) + (seg << 2);

            const float4 L0 = *(const float4*)&bg[gbase];
            const float4 L1 = *(const float4*)&bg[gbase + CH_STRIDE];
            const float4 L2 = *(const float4*)&bg[gbase + 2 * CH_STRIDE];
            const float4 L3 = *(const float4*)&bg[gbase + 3 * CH_STRIDE];

            float4 W0, W1;
            W0.x = PK(L0.x, L1.x); W0.y = PK(L2.x, L3.x);   // t = 4*seg+0
            W0.z = PK(L0.y, L1.y); W0.w = PK(L2.y, L3.y);   // t = 4*seg+1
            W1.x = PK(L0.z, L1.z); W1.y = PK(L2.z, L3.z);   // t = 4*seg+2
            W1.z = PK(L0.w, L1.w); W1.w = PK(L2.w, L3.w);   // t = 4*seg+3

            const int d = node * NODE_DW + (seg << 3);
            *(float4*)&lds[d] = W0;
            *(float4*)&lds[d + 4] = W1;
        }
    }
#undef PK
    // NO __syncthreads(): each wave reads only its own segment; intra-wave
    // ds_write -> ds_read ordering is enforced by lgkmcnt.

    // ---- interp constants ----
    const float xf = fminf((float)i * S_, 31.0f);
    const float yf = fminf((float)j * S_, 31.0f);
    const int x0g = (int)xf; const float fx = xf - (float)x0g;
    const int y0g = (int)yf; const float fy = yf - (float)y0g;
    const int AX0 = (x0g - x_base) * XS;
    const int AX1 = (min(x0g + 1, 31) - x_base) * XS;
    const int BY0 = (y0g - y_base) * YS;
    const int BY1 = (min(y0g + 1, 31) - y_base) * YS;

    const float wx1 = fx, wx0 = 1.0f - fx;
    const float wy1 = fy, wy0 = 1.0f - fy;
    const __half2 W00 = __float2half2_rn(wx0 * wy0);
    const __half2 W01 = __float2half2_rn(wx0 * wy1);
    const __half2 W10 = __float2half2_rn(wx1 * wy0);
    const __half2 W11 = __float2half2_rn(wx1 * wy1);

    float o0[4], o1[4], o2[4], o3[4];

#define H2(f) __builtin_bit_cast(__half2, f)
#pragma unroll
    for (int v = 0; v < 4; ++v) {
        const float g = (v == 0) ? g4.x : (v == 1) ? g4.y : (v == 2) ? g4.z : g4.w;
        float t = fminf(fmaxf(g * 15.0f, 0.0f), 15.0f);
        const int t0 = min((int)t, 14);
        const float ft = t - (float)t0;
        const __half2 ft2 = __float2half2_rn(ft);

        const float zf = fminf((float)(kk + v) * S_, 31.0f);
        const int z0g = (int)zf;
        const float fz = zf - (float)z0g;
        const int zi0 = z0g - z_base;
        const int zi1 = min(z0g + 1, 31) - z_base;
        const __half2 fz2 = __float2half2_rn(fz);

        const int CZ0 = zi0 * NODE_DW + (t0 << 1);
        const int CZ1 = zi1 * NODE_DW + (t0 << 1);

        const float2 a00lo = *(const float2*)&lds[AX0 + BY0 + CZ0];
        const float2 a00hi = *(const float2*)&lds[AX0 + BY0 + CZ0 + 2];
        const float2 a01lo = *(const float2*)&lds[AX0 + BY1 + CZ0];
        const float2 a01hi = *(const float2*)&lds[AX0 + BY1 + CZ0 + 2];
        const float2 a10lo = *(const float2*)&lds[AX1 + BY0 + CZ0];
        const float2 a10hi = *(const float2*)&lds[AX1 + BY0 + CZ0 + 2];
        const float2 a11lo = *(const float2*)&lds[AX1 + BY1 + CZ0];
        const float2 a11hi = *(const float2*)&lds[AX1 + BY1 + CZ0 + 2];
        const float2 b00lo = *(const float2*)&lds[AX0 + BY0 + CZ1];
        const float2 b00hi = *(const float2*)&lds[AX0 + BY0 + CZ1 + 2];
        const float2 b01lo = *(const float2*)&lds[AX0 + BY1 + CZ1];
        const float2 b01hi = *(const float2*)&lds[AX0 + BY1 + CZ1 + 2];
        const float2 b10lo = *(const float2*)&lds[AX1 + BY0 + CZ1];
        const float2 b10hi = *(const float2*)&lds[AX1 + BY0 + CZ1 + 2];
        const float2 b11lo = *(const float2*)&lds[AX1 + BY1 + CZ1];
        const float2 b11hi = *(const float2*)&lds[AX1 + BY1 + CZ1 + 2];

        __half2 Plo01 = __hmul2(W00, H2(a00lo.x));
        __half2 Plo23 = __hmul2(W00, H2(a00lo.y));
        __half2 Phi01 = __hmul2(W00, H2(a00hi.x));
        __half2 Phi23 = __hmul2(W00, H2(a00hi.y));
        Plo01 = __hfma2(W01, H2(a01lo.x), Plo01);
        Plo23 = __hfma2(W01, H2(a01lo.y), Plo23);
        Phi01 = __hfma2(W01, H2(a01hi.x), Phi01);
        Phi23 = __hfma2(W01, H2(a01hi.y), Phi23);
        Plo01 = __hfma2(W10, H2(a10lo.x), Plo01);
        Plo23 = __hfma2(W10, H2(a10lo.y), Plo23);
        Phi01 = __hfma2(W10, H2(a10hi.x), Phi01);
        Phi23 = __hfma2(W10, H2(a10hi.y), Phi23);
        Plo01 = __hfma2(W11, H2(a11lo.x), Plo01);
        Plo23 = __hfma2(W11, H2(a11lo.y), Plo23);
        Phi01 = __hfma2(W11, H2(a11hi.x), Phi01);
        Phi23 = __hfma2(W11, H2(a11hi.y), Phi23);

        __half2 Qlo01 = __hmul2(W00, H2(b00lo.x));
        __half2 Qlo23 = __hmul2(W00, H2(b00lo.y));
        __half2 Qhi01 = __hmul2(W00, H2(b00hi.x));
        __half2 Qhi23 = __hmul2(W00, H2(b00hi.y));
        Qlo01 = __hfma2(W01, H2(b01lo.x), Qlo01);
        Qlo23 = __hfma2(W01, H2(b01lo.y), Qlo23);
        Qhi01 = __hfma2(W01, H2(b01hi.x), Qhi01);
        Qhi23 = __hfma2(W01, H2(b01hi.y), Qhi23);
        Qlo01 = __hfma2(W10, H2(b10lo.x), Qlo01);
        Qlo23 = __hfma2(W10, H2(b10lo.y), Qlo23);
        Qhi01 = __hfma2(W10, H2(b10hi.x), Qhi01);
        Qhi23 = __hfma2(W10, H2(b10hi.y), Qhi23);
        Qlo01 = __hfma2(W11, H2(b11lo.x), Qlo01);
        Qlo23 = __hfma2(W11, H2(b11lo.y), Qlo23);
        Qhi01 = __hfma2(W11, H2(b11hi.x), Qhi01);
        Qhi23 = __hfma2(W11, H2(b11hi.y), Qhi23);

        const __half2 Rlo01 = __hfma2(fz2, __hsub2(Qlo01, Plo01), Plo01);
        const __half2 Rlo23 = __hfma2(fz2, __hsub2(Qlo23, Plo23), Plo23);
        const __half2 Rhi01 = __hfma2(fz2, __hsub2(Qhi01, Phi01), Phi01);
        const __half2 Rhi23 = __hfma2(fz2, __hsub2(Qhi23, Phi23), Phi23);

        const __half2 r01 = __hfma2(ft2, __hsub2(Rhi01, Rlo01), Rlo01);
        const __half2 r23 = __hfma2(ft2, __hsub2(Rhi23, Rlo23), Rlo23);

        o0[v] = __low2float(r01);
        o1[v] = __high2float(r01);
        o2[v] = __low2float(r23);
        o3[v] = __high2float(r23);
    }
#undef H2

    float4 st;
    st.x = o0[0]; st.y = o0[1]; st.z = o0[2]; st.w = o0[3];
    *(float4*)&out[idx] = st;
    st.x = o1[0]; st.y = o1[1]; st.z = o1[2]; st.w = o1[3];
    *(float4*)&out[idx + TOTAL] = st;
    st.x = o2[0]; st.y = o2[1]; st.z = o2[2]; st.w = o2[3];
    *(float4*)&out[idx + 2 * TOTAL] = st;
    st.x = o3[0]; st.y = o3[1]; st.z = o3[2]; st.w = o3[3];
    *(float4*)&out[idx + 3 * TOTAL] = st;
}

extern "C" void kernel_launch(void* const* d_in, const int* in_sizes, int n_in,
                              void* d_out, int out_size, void* d_ws, size_t ws_size,
                              hipStream_t stream) {
    const float* bg = (const float*)d_in[0];
    const float* gm = (const float*)d_in[1];
    float* out = (float*)d_out;

    dim3 grid(2048);   // 8192 waves = 32(i) * 32(j) * 8(k) tiles
    dim3 block(256);
    bgrid_slice_v9<<<grid, block, 0, stream>>>(bg, gm, out);
}